// Round 1
// baseline (763.248 us; speedup 1.0000x reference)
//
#include <hip/hip_runtime.h>

constexpr int NODE = 128;
constexpr int HID  = 64;

// --- W1 [NODE][HID] -> W1T [HID][NODE] so each hidden unit's weights are contiguous
__global__ void transpose_w1_kernel(const float* __restrict__ w1, float* __restrict__ w1t) {
    int t = blockIdx.x * blockDim.x + threadIdx.x;
    if (t < NODE * HID) {
        int j = t / NODE;
        int k = t - j * NODE;
        w1t[j * NODE + k] = w1[k * HID + j];
    }
}

// --- mass-weighted centroid accumulation: num[b*3+c] += m*pos, den[b] += m
__global__ void centroid_accum_kernel(const float* __restrict__ pos,
                                      const int* __restrict__ at_no,
                                      const int* __restrict__ batch,
                                      const float* __restrict__ masses,
                                      float* __restrict__ num,
                                      float* __restrict__ den,
                                      int n) {
    int i = blockIdx.x * blockDim.x + threadIdx.x;
    if (i >= n) return;
    int b = batch[i];
    float m = masses[at_no[i]];
    float px = pos[3 * i + 0];
    float py = pos[3 * i + 1];
    float pz = pos[3 * i + 2];
    atomicAdd(&den[b], m);
    atomicAdd(&num[3 * b + 0], m * px);
    atomicAdd(&num[3 * b + 1], m * py);
    atomicAdd(&num[3 * b + 2], m * pz);
}

// --- centroids = num / den (in place)
__global__ void centroid_div_kernel(float* __restrict__ num,
                                    const float* __restrict__ den,
                                    int nb) {
    int b = blockIdx.x * blockDim.x + threadIdx.x;
    if (b >= nb) return;
    float inv = 1.0f / den[b];
    num[3 * b + 0] *= inv;
    num[3 * b + 1] *= inv;
    num[3 * b + 2] *= inv;
}

// --- main: per-atom MLP (128->64 silu ->1) * squared distance to centroid,
//           scatter-add into out[batch[i]].
// One lane = one atom. x-row lives in 128 VGPRs (static indices only).
// W1T column / b1[j] / w2[j] are wave-uniform -> scalar loads -> free SGPR
// operand on v_fma_f32.
__global__ __launch_bounds__(256, 3) void spatial_main_kernel(
    const float* __restrict__ x,
    const float* __restrict__ pos,
    const int* __restrict__ batch,
    const float* __restrict__ cent,   // [nb*3], already divided
    const float* __restrict__ w1t,    // [HID*NODE]
    const float* __restrict__ b1,     // [HID]
    const float* __restrict__ w2,     // [HID]
    const float* __restrict__ b2,     // [1]
    float* __restrict__ out,          // [nb]
    int n) {
    int i = blockIdx.x * blockDim.x + threadIdx.x;
    if (i >= n) return;

    // load this atom's x row into registers (fully static indexing)
    float xr[NODE];
    const float4* xp = reinterpret_cast<const float4*>(x + (size_t)i * NODE);
#pragma unroll
    for (int k = 0; k < NODE / 4; ++k) {
        float4 v = xp[k];
        xr[4 * k + 0] = v.x;
        xr[4 * k + 1] = v.y;
        xr[4 * k + 2] = v.z;
        xr[4 * k + 3] = v.w;
    }

    float out_acc = 0.0f;
    for (int j = 0; j < HID; ++j) {
        const float* __restrict__ col = w1t + j * NODE;   // wave-uniform address
        float a0 = 0.0f, a1 = 0.0f, a2 = 0.0f, a3 = 0.0f;
#pragma unroll
        for (int k = 0; k < NODE; k += 4) {
            a0 = fmaf(xr[k + 0], col[k + 0], a0);
            a1 = fmaf(xr[k + 1], col[k + 1], a1);
            a2 = fmaf(xr[k + 2], col[k + 2], a2);
            a3 = fmaf(xr[k + 3], col[k + 3], a3);
        }
        float s = (a0 + a1) + (a2 + a3) + b1[j];
        // silu(s) = s * sigmoid(s)
        float h = s / (1.0f + __expf(-s));
        out_acc = fmaf(h, w2[j], out_acc);
    }
    out_acc += b2[0];

    int b = batch[i];
    float cx = cent[3 * b + 0];
    float cy = cent[3 * b + 1];
    float cz = cent[3 * b + 2];
    float dx = pos[3 * i + 0] - cx;
    float dy = pos[3 * i + 1] - cy;
    float dz = pos[3 * i + 2] - cz;
    float spatial = dx * dx + dy * dy + dz * dz;

    atomicAdd(&out[b], out_acc * spatial);
}

extern "C" void kernel_launch(void* const* d_in, const int* in_sizes, int n_in,
                              void* d_out, int out_size, void* d_ws, size_t ws_size,
                              hipStream_t stream) {
    const float* x      = (const float*)d_in[0];   // [N,128]
    const float* pos    = (const float*)d_in[1];   // [N,3]
    const int*   at_no  = (const int*)d_in[2];     // [N]
    const int*   batch  = (const int*)d_in[3];     // [N]
    const float* masses = (const float*)d_in[4];   // [119]
    const float* W1     = (const float*)d_in[5];   // [128,64]
    const float* b1     = (const float*)d_in[6];   // [64]
    const float* W2     = (const float*)d_in[7];   // [64,1]
    const float* b2     = (const float*)d_in[8];   // [1]

    int n  = in_sizes[2];   // N atoms
    int nb = out_size;      // B molecules

    float* out = (float*)d_out;
    float* ws  = (float*)d_ws;
    float* num = ws;                 // [nb*3]
    float* den = ws + 3 * (size_t)nb; // [nb]
    float* w1t = ws + 4 * (size_t)nb; // [HID*NODE]

    // zero accumulators (harness does not re-poison between replays)
    hipMemsetAsync(num, 0, (size_t)4 * nb * sizeof(float), stream);
    hipMemsetAsync(d_out, 0, (size_t)nb * sizeof(float), stream);

    transpose_w1_kernel<<<(NODE * HID + 255) / 256, 256, 0, stream>>>(W1, w1t);
    centroid_accum_kernel<<<(n + 255) / 256, 256, 0, stream>>>(pos, at_no, batch, masses,
                                                               num, den, n);
    centroid_div_kernel<<<(nb + 255) / 256, 256, 0, stream>>>(num, den, nb);
    spatial_main_kernel<<<(n + 255) / 256, 256, 0, stream>>>(x, pos, batch, num, w1t,
                                                             b1, W2, b2, out, n);
}